// Round 11
// baseline (333.637 us; speedup 1.0000x reference)
//
#include <hip/hip_runtime.h>

#define N_NODES 100000
#define IN_CH 128
#define HIDDEN 128
#define OUT_CH 64
#define N_POS 600000
#define N_NEG 600000

typedef unsigned int uint32;
typedef unsigned short ushort16;
typedef __attribute__((ext_vector_type(8))) short bf16x8;
typedef __attribute__((ext_vector_type(4))) float f32x4;

// ---- bf16 helpers ----
__device__ inline float bf_lo(uint32 u) {
    union { uint32 i; float f; } v;
    v.i = u << 16;
    return v.f;
}
__device__ inline float bf_hi(uint32 u) {
    union { uint32 i; float f; } v;
    v.i = u & 0xffff0000u;
    return v.f;
}
__device__ inline ushort16 f2bf(float f) {
    union { uint32 i; float f; } v;
    v.f = f;
    uint32 r = v.i + 0x7fffu + ((v.i >> 16) & 1u);  // round-to-nearest-even
    return (ushort16)(r >> 16);
}
__device__ inline uint32 pack2bf(float a, float b) {
    return (uint32)f2bf(a) | ((uint32)f2bf(b) << 16);
}

#define NB_HIST ((N_POS + 255) / 256)   // 2344
#define NB_FILL ((N_POS + 255) / 256)   // 2344
#define NB_GEMM1 ((N_NODES + 63) / 64)  // 1563

// ===== fused: hist_count + weight transpose/convert (independent work) =====
__global__ void hist_wt(const int* __restrict__ dst, int* __restrict__ hist,
                        const float* __restrict__ W1, const float* __restrict__ W2,
                        ushort16* __restrict__ W1t, ushort16* __restrict__ W2t) {
    if (blockIdx.x < NB_HIST) {
        int i = blockIdx.x * 256 + threadIdx.x;
        if (i < N_POS) atomicAdd(&hist[dst[i]], 1);
    } else {
        int i = (blockIdx.x - NB_HIST) * 256 + threadIdx.x;
        if (i < 128 * 128) {
            int n = i >> 7, k = i & 127;
            W1t[i] = f2bf(W1[k * 128 + n]);
        } else {
            int j = i - 128 * 128;
            if (j < 64 * 128) {
                int n = j >> 7, k = j & 127;
                W2t[j] = f2bf(W2[k * 64 + n]);
            }
        }
    }
}

__global__ void scan_reduce(const int* __restrict__ hist, int* __restrict__ partials, int n) {
    __shared__ int sdata[256];
    int b = blockIdx.x, t = threadIdx.x;
    int base = b * 1024;
    int s = 0;
    for (int i = t; i < 1024; i += 256) {
        int idx = base + i;
        s += (idx < n) ? hist[idx] : 0;
    }
    sdata[t] = s;
    __syncthreads();
    for (int off = 128; off > 0; off >>= 1) {
        if (t < off) sdata[t] += sdata[t + off];
        __syncthreads();
    }
    if (t == 0) partials[b] = sdata[0];
}

// scan_final computes its own partials-prefix (first wave). NB_SCAN = 98 <= 128.
__global__ void scan_final(const int* __restrict__ hist, const int* __restrict__ partials,
                           int* __restrict__ rowstart, int* __restrict__ cursor,
                           float* __restrict__ dinv, int n) {
    __shared__ int tsum[256];
    __shared__ int base_sh;
    int t = threadIdx.x, b = blockIdx.x;
    if (t < 64) {
        int s0 = (t < b) ? partials[t] : 0;
        int i2 = t + 64;
        int s1 = (i2 < b && i2 < 98) ? partials[i2] : 0;
        int s = s0 + s1;
#pragma unroll
        for (int off = 32; off > 0; off >>= 1) s += __shfl_down(s, off, 64);
        if (t == 0) base_sh = s;
    }
    int base = b * 1024 + t * 4;
    int v[4];
    int s = 0;
#pragma unroll
    for (int j = 0; j < 4; j++) {
        int i = base + j;
        v[j] = (i < n) ? hist[i] : 0;
        s += v[j];
    }
    tsum[t] = s;
    __syncthreads();
    for (int off = 1; off < 256; off <<= 1) {
        int a = (t >= off) ? tsum[t - off] : 0;
        __syncthreads();
        tsum[t] += a;
        __syncthreads();
    }
    int offset = base_sh + (tsum[t] - s);
#pragma unroll
    for (int j = 0; j < 4; j++) {
        int i = base + j;
        if (i < n) {
            rowstart[i] = offset;
            cursor[i] = offset;
            dinv[i] = rsqrtf((float)v[j] + 1.0f);
            offset += v[j];
        }
    }
    if (b == 0 && t == 0) rowstart[n] = N_POS;
}

// ===== shared GEMM tile body: H_bf16[node0..node0+64, M] = X @ W =====
// B-fragments read DIRECT from global (Wt is 16-32KB, L2-hot, same for all
// blocks) — no Ws LDS staging. LDS = X tile only (17.4KB) so co-scheduled
// scatter blocks keep high occupancy.
template <int M, bool XBF>
__device__ __forceinline__ void gemm_tile(const void* __restrict__ Xv,
                                          const ushort16* __restrict__ Wt,
                                          ushort16* __restrict__ H, int n, int tileIdx) {
    constexpr int K = 128;
    constexpr int TN = 64;
    constexpr int XS = 136;  // padded LDS row stride (shorts)
    __shared__ short Xs[TN * XS];
    int tid = threadIdx.x;
    int node0 = tileIdx * TN;

    if (!XBF) {
        const float* X = (const float*)Xv;
        int row = tid >> 2, part = tid & 3;
        int gn = node0 + row;
#pragma unroll
        for (int c = 0; c < 8; ++c) {
            int k = part * 32 + c * 4;
            float4 v = (gn < n) ? *(const float4*)(X + (size_t)gn * K + k) : float4{0, 0, 0, 0};
            uint2 p = {pack2bf(v.x, v.y), pack2bf(v.z, v.w)};
            *(uint2*)(Xs + row * XS + k) = p;
        }
    } else {
        const ushort16* X = (const ushort16*)Xv;
        for (int q = tid; q < TN * K / 8; q += 256) {
            int row = q >> 4;
            int c = q & 15;
            int gn = node0 + row;
            uint4 v = (gn < n) ? ((const uint4*)(X + (size_t)gn * K))[c] : uint4{0, 0, 0, 0};
            *(uint4*)(Xs + row * XS + c * 8) = v;
        }
    }
    __syncthreads();

    constexpr int CT = M / 16;
    int w = tid >> 6;
    int lane = tid & 63;
    int l15 = lane & 15;
    int quad = lane >> 4;

    f32x4 acc[CT] = {};
    const short* xrow = Xs + (w * 16 + l15) * XS + quad * 8;
    bf16x8 a[4];
#pragma unroll
    for (int kk = 0; kk < 4; ++kk) a[kk] = *(const bf16x8*)(xrow + kk * 32);

    const short* wrow = (const short*)Wt + l15 * K + quad * 8;
#pragma unroll
    for (int kk = 0; kk < 4; ++kk) {
#pragma unroll
        for (int ct = 0; ct < CT; ++ct) {
            bf16x8 b = *(const bf16x8*)(wrow + ct * 16 * K + kk * 32);
            acc[ct] = __builtin_amdgcn_mfma_f32_16x16x32_bf16(a[kk], b, acc[ct], 0, 0, 0);
        }
    }

#pragma unroll
    for (int ct = 0; ct < CT; ++ct) {
#pragma unroll
        for (int r = 0; r < 4; ++r) {
            int gn = node0 + w * 16 + quad * 4 + r;
            if (gn < n) H[(size_t)gn * M + ct * 16 + l15] = f2bf(acc[ct][r]);
        }
    }
}

// ===== fused: csr_fill (scattered, latency-bound) + layer-1 GEMM (MFMA-bound) =====
// CSR payload is src only (4B/edge) — wgt recomputed in agg_pull from dinv.
__global__ __launch_bounds__(256) void csr_gemm1(
    const int* __restrict__ src, const int* __restrict__ dst, int* __restrict__ cursor,
    int* __restrict__ adj, const float* __restrict__ x, const ushort16* __restrict__ W1t,
    ushort16* __restrict__ H, int n) {
    if (blockIdx.x < NB_FILL) {
        int e = blockIdx.x * 256 + threadIdx.x;
        if (e < N_POS) {
            int s = src[e], d = dst[e];
            int p = atomicAdd(&cursor[d], 1);
            adj[p] = s;
        }
    } else {
        gemm_tile<HIDDEN, false>(x, W1t, H, n, blockIdx.x - NB_FILL);
    }
}

// standalone layer-2 GEMM
template <int M, bool XBF>
__global__ __launch_bounds__(256) void gemm_mfma(const void* __restrict__ Xv,
                                                 const ushort16* __restrict__ Wt,
                                                 ushort16* __restrict__ H, int n) {
    gemm_tile<M, XBF>(Xv, Wt, H, n, blockIdx.x);
}

// ========= fused pull aggregation + self-loop + bias (+relu), bf16 H/Z =========
// FOUR nodes per wave (16 lanes each). Predicated straight-line 8-edge block:
// adj broadcast load -> {dinv[s] gather, H-row gather} all independent across
// the 8 slots; serial loop only for the rare deg>8 tail.
template <int F, bool RELU>
__global__ void agg_pull(const int* __restrict__ rowstart, const int* __restrict__ adj,
                         const float* __restrict__ dinv, const ushort16* __restrict__ H,
                         const float* __restrict__ bias, ushort16* __restrict__ Z, int n) {
    int g = threadIdx.x >> 4;  // 16-lane group
    int l = threadIdx.x & 15;
    int node = blockIdx.x * (blockDim.x >> 4) + g;
    if (node >= n) return;
    float dn = dinv[node];
    int rs = rowstart[node], re = rowstart[node + 1];
    int deg = re - rs;
    int pc = (deg > 0) ? rs : (rs > 0 ? rs - 1 : 0);  // safe clamp index
    if (F == 128) {
        uint4 h[8];
        float wv[8];
#pragma unroll
        for (int j = 0; j < 8; ++j) {
            int p = (rs + j < re) ? rs + j : pc;
            int s = adj[p];
            h[j] = *(const uint4*)(H + (size_t)s * F + l * 8);
            wv[j] = (j < deg) ? dinv[s] * dn : 0.0f;
        }
        float s0[8] = {}, s1[8] = {};
#pragma unroll
        for (int j = 0; j < 8; j += 2) {
            s0[0] += bf_lo(h[j].x) * wv[j]; s0[1] += bf_hi(h[j].x) * wv[j];
            s0[2] += bf_lo(h[j].y) * wv[j]; s0[3] += bf_hi(h[j].y) * wv[j];
            s0[4] += bf_lo(h[j].z) * wv[j]; s0[5] += bf_hi(h[j].z) * wv[j];
            s0[6] += bf_lo(h[j].w) * wv[j]; s0[7] += bf_hi(h[j].w) * wv[j];
            s1[0] += bf_lo(h[j + 1].x) * wv[j + 1]; s1[1] += bf_hi(h[j + 1].x) * wv[j + 1];
            s1[2] += bf_lo(h[j + 1].y) * wv[j + 1]; s1[3] += bf_hi(h[j + 1].y) * wv[j + 1];
            s1[4] += bf_lo(h[j + 1].z) * wv[j + 1]; s1[5] += bf_hi(h[j + 1].z) * wv[j + 1];
            s1[6] += bf_lo(h[j + 1].w) * wv[j + 1]; s1[7] += bf_hi(h[j + 1].w) * wv[j + 1];
        }
        for (int p = rs + 8; p < re; ++p) {
            int s = adj[p];
            float w = dinv[s] * dn;
            uint4 hh = *(const uint4*)(H + (size_t)s * F + l * 8);
            s0[0] += bf_lo(hh.x) * w; s0[1] += bf_hi(hh.x) * w;
            s0[2] += bf_lo(hh.y) * w; s0[3] += bf_hi(hh.y) * w;
            s0[4] += bf_lo(hh.z) * w; s0[5] += bf_hi(hh.z) * w;
            s0[6] += bf_lo(hh.w) * w; s0[7] += bf_hi(hh.w) * w;
        }
        uint4 hv = *(const uint4*)(H + (size_t)node * F + l * 8);
        float4 bv0 = *(const float4*)(bias + l * 8);
        float4 bv1 = *(const float4*)(bias + l * 8 + 4);
        float d2 = dn * dn;
        float hs[8] = {bf_lo(hv.x), bf_hi(hv.x), bf_lo(hv.y), bf_hi(hv.y),
                       bf_lo(hv.z), bf_hi(hv.z), bf_lo(hv.w), bf_hi(hv.w)};
        float bb[8] = {bv0.x, bv0.y, bv0.z, bv0.w, bv1.x, bv1.y, bv1.z, bv1.w};
        float v[8];
#pragma unroll
        for (int j = 0; j < 8; ++j) {
            v[j] = s0[j] + s1[j] + hs[j] * d2 + bb[j];
            if (RELU) v[j] = fmaxf(v[j], 0.0f);
        }
        *(uint4*)(Z + (size_t)node * F + l * 8) =
            uint4{pack2bf(v[0], v[1]), pack2bf(v[2], v[3]), pack2bf(v[4], v[5]),
                  pack2bf(v[6], v[7])};
    } else {  // F == 64
        uint2 h[8];
        float wv[8];
#pragma unroll
        for (int j = 0; j < 8; ++j) {
            int p = (rs + j < re) ? rs + j : pc;
            int s = adj[p];
            h[j] = *(const uint2*)(H + (size_t)s * F + l * 4);
            wv[j] = (j < deg) ? dinv[s] * dn : 0.0f;
        }
        float s0[4] = {}, s1[4] = {};
#pragma unroll
        for (int j = 0; j < 8; j += 2) {
            s0[0] += bf_lo(h[j].x) * wv[j]; s0[1] += bf_hi(h[j].x) * wv[j];
            s0[2] += bf_lo(h[j].y) * wv[j]; s0[3] += bf_hi(h[j].y) * wv[j];
            s1[0] += bf_lo(h[j + 1].x) * wv[j + 1]; s1[1] += bf_hi(h[j + 1].x) * wv[j + 1];
            s1[2] += bf_lo(h[j + 1].y) * wv[j + 1]; s1[3] += bf_hi(h[j + 1].y) * wv[j + 1];
        }
        for (int p = rs + 8; p < re; ++p) {
            int s = adj[p];
            float w = dinv[s] * dn;
            uint2 hh = *(const uint2*)(H + (size_t)s * F + l * 4);
            s0[0] += bf_lo(hh.x) * w; s0[1] += bf_hi(hh.x) * w;
            s0[2] += bf_lo(hh.y) * w; s0[3] += bf_hi(hh.y) * w;
        }
        uint2 hv = *(const uint2*)(H + (size_t)node * F + l * 4);
        float4 bv = *(const float4*)(bias + l * 4);
        float d2 = dn * dn;
        float hs[4] = {bf_lo(hv.x), bf_hi(hv.x), bf_lo(hv.y), bf_hi(hv.y)};
        float bb[4] = {bv.x, bv.y, bv.z, bv.w};
        float v[4];
#pragma unroll
        for (int j = 0; j < 4; ++j) {
            v[j] = s0[j] + s1[j] + hs[j] * d2 + bb[j];
            if (RELU) v[j] = fmaxf(v[j], 0.0f);
        }
        *(uint2*)(Z + (size_t)node * F + l * 4) = uint2{pack2bf(v[0], v[1]), pack2bf(v[2], v[3])};
    }
}

// ===== decode via MFMA: 32 edges per wave (two 16-edge groups) =====
__global__ void decode_mfma(const int* __restrict__ pos, const int* __restrict__ neg,
                            const short* __restrict__ Z, float* __restrict__ out) {
    int wid = threadIdx.x >> 6;
    int lane = threadIdx.x & 63;
    int l15 = lane & 15;
    int quad = lane >> 4;
    int e0 = (blockIdx.x * 4 + wid) * 32;
    if (e0 >= N_POS + N_NEG) return;
    const int* bp = (e0 < N_POS) ? pos : (neg - N_POS);
    int eA = e0 + l15;
    int eB = e0 + 16 + l15;
    int aA = bp[eA], bA = bp[600000 + eA];
    int aB = bp[eB], bB = bp[600000 + eB];

    const short* zaA = Z + (size_t)aA * OUT_CH + quad * 8;
    const short* zbA = Z + (size_t)bA * OUT_CH + quad * 8;
    const short* zaB = Z + (size_t)aB * OUT_CH + quad * 8;
    const short* zbB = Z + (size_t)bB * OUT_CH + quad * 8;
    bf16x8 a0A = *(const bf16x8*)(zaA);
    bf16x8 a1A = *(const bf16x8*)(zaA + 32);
    bf16x8 b0A = *(const bf16x8*)(zbA);
    bf16x8 b1A = *(const bf16x8*)(zbA + 32);
    bf16x8 a0B = *(const bf16x8*)(zaB);
    bf16x8 a1B = *(const bf16x8*)(zaB + 32);
    bf16x8 b0B = *(const bf16x8*)(zbB);
    bf16x8 b1B = *(const bf16x8*)(zbB + 32);

    f32x4 accA = {}, accB = {};
    accA = __builtin_amdgcn_mfma_f32_16x16x32_bf16(a0A, b0A, accA, 0, 0, 0);
    accB = __builtin_amdgcn_mfma_f32_16x16x32_bf16(a0B, b0B, accB, 0, 0, 0);
    accA = __builtin_amdgcn_mfma_f32_16x16x32_bf16(a1A, b1A, accA, 0, 0, 0);
    accB = __builtin_amdgcn_mfma_f32_16x16x32_bf16(a1B, b1B, accB, 0, 0, 0);

    if (quad == (l15 >> 2)) {
        out[eA] = accA[l15 & 3];
        out[eB] = accB[l15 & 3];
    }
}

extern "C" void kernel_launch(void* const* d_in, const int* in_sizes, int n_in,
                              void* d_out, int out_size, void* d_ws, size_t ws_size,
                              hipStream_t stream) {
    const float* x = (const float*)d_in[0];
    const int* pos = (const int*)d_in[1];  // row0 = src, row1 = dst
    const int* neg = (const int*)d_in[2];
    const float* W1 = (const float*)d_in[3];
    const float* b1 = (const float*)d_in[4];
    const float* W2 = (const float*)d_in[5];
    const float* b2 = (const float*)d_in[6];
    float* out = (float*)d_out;

    // workspace layout (bf16 intermediates)
    ushort16* A = (ushort16*)d_ws;                      // h1 [N,128]; later h2 [N,64]
    ushort16* B = A + (size_t)N_NODES * 128;            // z1 [N,128]; later z2 [N,64]
    float* dinv = (float*)(B + (size_t)N_NODES * 128);  // [N]
    int* hist = (int*)(dinv + N_NODES);                 // [N]
    int* rowstart = hist + N_NODES;                     // [N+1]
    int* cursor = rowstart + N_NODES + 1;               // [N]
    int* adj = cursor + N_NODES;                        // [N_POS] (src only, 4B/edge)
    int* partials = adj + N_POS;                        // [128]
    ushort16* W1t = (ushort16*)(partials + 128);        // [128*128]
    ushort16* W2t = W1t + 128 * 128;                    // [64*128]

    const int* pos_src = pos;
    const int* pos_dst = pos + N_POS;

    constexpr int NB_SCAN = (N_NODES + 1023) / 1024;  // 98

    // ---- CSR build + dinv + weight convert ----
    hipMemsetAsync(hist, 0, N_NODES * sizeof(int), stream);
    hist_wt<<<NB_HIST + 96, 256, 0, stream>>>(pos_dst, hist, W1, W2, W1t, W2t);
    scan_reduce<<<NB_SCAN, 256, 0, stream>>>(hist, partials, N_NODES);
    scan_final<<<NB_SCAN, 256, 0, stream>>>(hist, partials, rowstart, cursor, dinv, N_NODES);

    // ---- csr_fill + layer-1 GEMM fused (independent work, one launch) ----
    csr_gemm1<<<NB_FILL + NB_GEMM1, 256, 0, stream>>>(pos_src, pos_dst, cursor, adj, x, W1t, A,
                                                      N_NODES);

    // ---- layer 1 aggregation ----
    agg_pull<HIDDEN, true><<<(N_NODES + 15) / 16, 256, 0, stream>>>(rowstart, adj, dinv, A, b1, B,
                                                                    N_NODES);

    // ---- layer 2 ----
    ushort16* h2 = A;  // [N,64]
    gemm_mfma<OUT_CH, true><<<(N_NODES + 63) / 64, 256, 0, stream>>>(B, W2t, h2, N_NODES);
    ushort16* z2 = B;  // [N,64]
    agg_pull<OUT_CH, false><<<(N_NODES + 15) / 16, 256, 0, stream>>>(rowstart, adj, dinv, h2, b2,
                                                                     z2, N_NODES);

    // ---- decode (32 edges/wave, 128/block) ----
    decode_mfma<<<(N_POS + N_NEG) / 128, 256, 0, stream>>>(pos, neg, (const short*)z2, out);
}

// Round 12
// 268.865 us; speedup vs baseline: 1.2409x; 1.2409x over previous
//
#include <hip/hip_runtime.h>

#define N_NODES 100000
#define IN_CH 128
#define HIDDEN 128
#define OUT_CH 64
#define N_POS 600000
#define N_NEG 600000

typedef unsigned int uint32;
typedef unsigned short ushort16;
typedef __attribute__((ext_vector_type(8))) short bf16x8;
typedef __attribute__((ext_vector_type(4))) float f32x4;

// ---- bf16 helpers ----
__device__ inline float bf_lo(uint32 u) {
    union { uint32 i; float f; } v;
    v.i = u << 16;
    return v.f;
}
__device__ inline float bf_hi(uint32 u) {
    union { uint32 i; float f; } v;
    v.i = u & 0xffff0000u;
    return v.f;
}
__device__ inline ushort16 f2bf(float f) {
    union { uint32 i; float f; } v;
    v.f = f;
    uint32 r = v.i + 0x7fffu + ((v.i >> 16) & 1u);  // round-to-nearest-even
    return (ushort16)(r >> 16);
}
__device__ inline uint32 pack2bf(float a, float b) {
    return (uint32)f2bf(a) | ((uint32)f2bf(b) << 16);
}

#define NB_HIST ((N_POS + 255) / 256)   // 2344
#define NB_FILL ((N_POS + 255) / 256)   // 2344
#define NB_GEMM1 ((N_NODES + 63) / 64)  // 1563

// ===== fused: hist_count + weight transpose/convert (independent work) =====
__global__ void hist_wt(const int* __restrict__ dst, int* __restrict__ hist,
                        const float* __restrict__ W1, const float* __restrict__ W2,
                        ushort16* __restrict__ W1t, ushort16* __restrict__ W2t) {
    if (blockIdx.x < NB_HIST) {
        int i = blockIdx.x * 256 + threadIdx.x;
        if (i < N_POS) atomicAdd(&hist[dst[i]], 1);
    } else {
        int i = (blockIdx.x - NB_HIST) * 256 + threadIdx.x;
        if (i < 128 * 128) {
            int n = i >> 7, k = i & 127;
            W1t[i] = f2bf(W1[k * 128 + n]);
        } else {
            int j = i - 128 * 128;
            if (j < 64 * 128) {
                int n = j >> 7, k = j & 127;
                W2t[j] = f2bf(W2[k * 64 + n]);
            }
        }
    }
}

__global__ void scan_reduce(const int* __restrict__ hist, int* __restrict__ partials, int n) {
    __shared__ int sdata[256];
    int b = blockIdx.x, t = threadIdx.x;
    int base = b * 1024;
    int s = 0;
    for (int i = t; i < 1024; i += 256) {
        int idx = base + i;
        s += (idx < n) ? hist[idx] : 0;
    }
    sdata[t] = s;
    __syncthreads();
    for (int off = 128; off > 0; off >>= 1) {
        if (t < off) sdata[t] += sdata[t + off];
        __syncthreads();
    }
    if (t == 0) partials[b] = sdata[0];
}

// scan_final computes its own partials-prefix (first wave). NB_SCAN = 98 <= 128.
__global__ void scan_final(const int* __restrict__ hist, const int* __restrict__ partials,
                           int* __restrict__ rowstart, int* __restrict__ cursor,
                           float* __restrict__ dinv, int n) {
    __shared__ int tsum[256];
    __shared__ int base_sh;
    int t = threadIdx.x, b = blockIdx.x;
    if (t < 64) {
        int s0 = (t < b) ? partials[t] : 0;
        int i2 = t + 64;
        int s1 = (i2 < b && i2 < 98) ? partials[i2] : 0;
        int s = s0 + s1;
#pragma unroll
        for (int off = 32; off > 0; off >>= 1) s += __shfl_down(s, off, 64);
        if (t == 0) base_sh = s;
    }
    int base = b * 1024 + t * 4;
    int v[4];
    int s = 0;
#pragma unroll
    for (int j = 0; j < 4; j++) {
        int i = base + j;
        v[j] = (i < n) ? hist[i] : 0;
        s += v[j];
    }
    tsum[t] = s;
    __syncthreads();
    for (int off = 1; off < 256; off <<= 1) {
        int a = (t >= off) ? tsum[t - off] : 0;
        __syncthreads();
        tsum[t] += a;
        __syncthreads();
    }
    int offset = base_sh + (tsum[t] - s);
#pragma unroll
    for (int j = 0; j < 4; j++) {
        int i = base + j;
        if (i < n) {
            rowstart[i] = offset;
            cursor[i] = offset;
            dinv[i] = rsqrtf((float)v[j] + 1.0f);
            offset += v[j];
        }
    }
    if (b == 0 && t == 0) rowstart[n] = N_POS;
}

// ===== shared GEMM tile body: H_bf16[node0..node0+64, M] = X @ W =====
// K-split double staging: LDS holds only a K/2 slice of X-tile and W at a
// time (27.6KB for M=128 vs 52KB full) so co-scheduled scatter blocks keep
// ~5 blocks/CU occupancy. W staged through LDS (coalesced once, broadcast
// reads) — round-11 direct-global W was a 1.7x regression.
template <int M, bool XBF>
__device__ __forceinline__ void gemm_tile(const void* __restrict__ Xv,
                                          const ushort16* __restrict__ Wt,
                                          ushort16* __restrict__ H, int n, int tileIdx) {
    constexpr int K = 128;
    constexpr int TN = 64;
    constexpr int KH = 64;  // K half
    constexpr int XS = 72;  // padded half-row stride (shorts): 144B -> 2-way bank alias (free)
    __shared__ short Xs[TN * XS];
    __shared__ short Ws[M * XS];
    int tid = threadIdx.x;
    int node0 = tileIdx * TN;

    constexpr int CT = M / 16;
    int w = tid >> 6;
    int lane = tid & 63;
    int l15 = lane & 15;
    int quad = lane >> 4;
    f32x4 acc[CT] = {};

#pragma unroll
    for (int h = 0; h < 2; ++h) {
        if (h) __syncthreads();  // all waves done reading previous half
        // stage W half: M rows x 64 shorts (128B contiguous per row)
        for (int q = tid; q < M * 8; q += 256) {
            int row = q >> 3, c = q & 7;
            uint4 v = *(const uint4*)((const short*)Wt + row * K + h * KH + c * 8);
            *(uint4*)(Ws + row * XS + c * 8) = v;
        }
        // stage X half
        if (!XBF) {
            const float* X = (const float*)Xv;
            int row = tid >> 2, part = tid & 3;  // 4 threads/row, 16 floats each
            int gn = node0 + row;
#pragma unroll
            for (int c = 0; c < 4; ++c) {
                int kl = part * 16 + c * 4;  // local k within half
                float4 v = (gn < n) ? *(const float4*)(X + (size_t)gn * K + h * KH + kl)
                                    : float4{0, 0, 0, 0};
                uint2 p = {pack2bf(v.x, v.y), pack2bf(v.z, v.w)};
                *(uint2*)(Xs + row * XS + kl) = p;
            }
        } else {
            const short* X = (const short*)Xv;
            for (int q = tid; q < TN * 8; q += 256) {
                int row = q >> 3, c = q & 7;
                int gn = node0 + row;
                uint4 v = (gn < n) ? *(const uint4*)(X + (size_t)gn * K + h * KH + c * 8)
                                   : uint4{0, 0, 0, 0};
                *(uint4*)(Xs + row * XS + c * 8) = v;
            }
        }
        __syncthreads();

        const short* xrow = Xs + (w * 16 + l15) * XS + quad * 8;
#pragma unroll
        for (int kk = 0; kk < 2; ++kk) {
            bf16x8 a = *(const bf16x8*)(xrow + kk * 32);
#pragma unroll
            for (int ct = 0; ct < CT; ++ct) {
                bf16x8 b = *(const bf16x8*)(Ws + (ct * 16 + l15) * XS + quad * 8 + kk * 32);
                acc[ct] = __builtin_amdgcn_mfma_f32_16x16x32_bf16(a, b, acc[ct], 0, 0, 0);
            }
        }
    }

#pragma unroll
    for (int ct = 0; ct < CT; ++ct) {
#pragma unroll
        for (int r = 0; r < 4; ++r) {
            int gn = node0 + w * 16 + quad * 4 + r;
            if (gn < n) H[(size_t)gn * M + ct * 16 + l15] = f2bf(acc[ct][r]);
        }
    }
}

// ===== fused: csr_fill (scattered, latency-bound) + layer-1 GEMM (MFMA-bound) =====
__global__ __launch_bounds__(256) void csr_gemm1(
    const int* __restrict__ src, const int* __restrict__ dst, const float* __restrict__ dinv,
    int* __restrict__ cursor, int2* __restrict__ adjw, const float* __restrict__ x,
    const ushort16* __restrict__ W1t, ushort16* __restrict__ H, int n) {
    if (blockIdx.x < NB_FILL) {
        int e = blockIdx.x * 256 + threadIdx.x;
        if (e < N_POS) {
            int s = src[e], d = dst[e];
            int p = atomicAdd(&cursor[d], 1);
            adjw[p] = int2{s, __float_as_int(dinv[s] * dinv[d])};
        }
    } else {
        gemm_tile<HIDDEN, false>(x, W1t, H, n, blockIdx.x - NB_FILL);
    }
}

// standalone layer-2 GEMM
template <int M, bool XBF>
__global__ __launch_bounds__(256) void gemm_mfma(const void* __restrict__ Xv,
                                                 const ushort16* __restrict__ Wt,
                                                 ushort16* __restrict__ H, int n) {
    gemm_tile<M, XBF>(Xv, Wt, H, n, blockIdx.x);
}

// ========= fused pull aggregation + self-loop + bias (+relu), bf16 H/Z =========
// FOUR nodes per wave (16 lanes each). Predicated straight-line 8-edge block.
template <int F, bool RELU>
__global__ void agg_pull(const int* __restrict__ rowstart, const int2* __restrict__ adjw,
                         const float* __restrict__ dinv, const ushort16* __restrict__ H,
                         const float* __restrict__ bias, ushort16* __restrict__ Z, int n) {
    int g = threadIdx.x >> 4;  // 16-lane group
    int l = threadIdx.x & 15;
    int node = blockIdx.x * (blockDim.x >> 4) + g;
    if (node >= n) return;
    float dn = dinv[node];
    int rs = rowstart[node], re = rowstart[node + 1];
    int deg = re - rs;
    int pc = (deg > 0) ? rs : (rs > 0 ? rs - 1 : 0);  // safe clamp index
    if (F == 128) {
        uint4 h[8];
        float wv[8];
#pragma unroll
        for (int j = 0; j < 8; ++j) {
            int p = (rs + j < re) ? rs + j : pc;
            int2 e = adjw[p];
            h[j] = *(const uint4*)(H + (size_t)e.x * F + l * 8);
            wv[j] = (j < deg) ? __int_as_float(e.y) : 0.0f;
        }
        float s0[8] = {}, s1[8] = {};
#pragma unroll
        for (int j = 0; j < 8; j += 2) {
            s0[0] += bf_lo(h[j].x) * wv[j]; s0[1] += bf_hi(h[j].x) * wv[j];
            s0[2] += bf_lo(h[j].y) * wv[j]; s0[3] += bf_hi(h[j].y) * wv[j];
            s0[4] += bf_lo(h[j].z) * wv[j]; s0[5] += bf_hi(h[j].z) * wv[j];
            s0[6] += bf_lo(h[j].w) * wv[j]; s0[7] += bf_hi(h[j].w) * wv[j];
            s1[0] += bf_lo(h[j + 1].x) * wv[j + 1]; s1[1] += bf_hi(h[j + 1].x) * wv[j + 1];
            s1[2] += bf_lo(h[j + 1].y) * wv[j + 1]; s1[3] += bf_hi(h[j + 1].y) * wv[j + 1];
            s1[4] += bf_lo(h[j + 1].z) * wv[j + 1]; s1[5] += bf_hi(h[j + 1].z) * wv[j + 1];
            s1[6] += bf_lo(h[j + 1].w) * wv[j + 1]; s1[7] += bf_hi(h[j + 1].w) * wv[j + 1];
        }
        for (int p = rs + 8; p < re; ++p) {
            int2 e = adjw[p];
            float w = __int_as_float(e.y);
            uint4 hh = *(const uint4*)(H + (size_t)e.x * F + l * 8);
            s0[0] += bf_lo(hh.x) * w; s0[1] += bf_hi(hh.x) * w;
            s0[2] += bf_lo(hh.y) * w; s0[3] += bf_hi(hh.y) * w;
            s0[4] += bf_lo(hh.z) * w; s0[5] += bf_hi(hh.z) * w;
            s0[6] += bf_lo(hh.w) * w; s0[7] += bf_hi(hh.w) * w;
        }
        uint4 hv = *(const uint4*)(H + (size_t)node * F + l * 8);
        float4 bv0 = *(const float4*)(bias + l * 8);
        float4 bv1 = *(const float4*)(bias + l * 8 + 4);
        float d2 = dn * dn;
        float hs[8] = {bf_lo(hv.x), bf_hi(hv.x), bf_lo(hv.y), bf_hi(hv.y),
                       bf_lo(hv.z), bf_hi(hv.z), bf_lo(hv.w), bf_hi(hv.w)};
        float bb[8] = {bv0.x, bv0.y, bv0.z, bv0.w, bv1.x, bv1.y, bv1.z, bv1.w};
        float v[8];
#pragma unroll
        for (int j = 0; j < 8; ++j) {
            v[j] = s0[j] + s1[j] + hs[j] * d2 + bb[j];
            if (RELU) v[j] = fmaxf(v[j], 0.0f);
        }
        *(uint4*)(Z + (size_t)node * F + l * 8) =
            uint4{pack2bf(v[0], v[1]), pack2bf(v[2], v[3]), pack2bf(v[4], v[5]),
                  pack2bf(v[6], v[7])};
    } else {  // F == 64
        uint2 h[8];
        float wv[8];
#pragma unroll
        for (int j = 0; j < 8; ++j) {
            int p = (rs + j < re) ? rs + j : pc;
            int2 e = adjw[p];
            h[j] = *(const uint2*)(H + (size_t)e.x * F + l * 4);
            wv[j] = (j < deg) ? __int_as_float(e.y) : 0.0f;
        }
        float s0[4] = {}, s1[4] = {};
#pragma unroll
        for (int j = 0; j < 8; j += 2) {
            s0[0] += bf_lo(h[j].x) * wv[j]; s0[1] += bf_hi(h[j].x) * wv[j];
            s0[2] += bf_lo(h[j].y) * wv[j]; s0[3] += bf_hi(h[j].y) * wv[j];
            s1[0] += bf_lo(h[j + 1].x) * wv[j + 1]; s1[1] += bf_hi(h[j + 1].x) * wv[j + 1];
            s1[2] += bf_lo(h[j + 1].y) * wv[j + 1]; s1[3] += bf_hi(h[j + 1].y) * wv[j + 1];
        }
        for (int p = rs + 8; p < re; ++p) {
            int2 e = adjw[p];
            float w = __int_as_float(e.y);
            uint2 hh = *(const uint2*)(H + (size_t)e.x * F + l * 4);
            s0[0] += bf_lo(hh.x) * w; s0[1] += bf_hi(hh.x) * w;
            s0[2] += bf_lo(hh.y) * w; s0[3] += bf_hi(hh.y) * w;
        }
        uint2 hv = *(const uint2*)(H + (size_t)node * F + l * 4);
        float4 bv = *(const float4*)(bias + l * 4);
        float d2 = dn * dn;
        float hs[4] = {bf_lo(hv.x), bf_hi(hv.x), bf_lo(hv.y), bf_hi(hv.y)};
        float bb[4] = {bv.x, bv.y, bv.z, bv.w};
        float v[4];
#pragma unroll
        for (int j = 0; j < 4; ++j) {
            v[j] = s0[j] + s1[j] + hs[j] * d2 + bb[j];
            if (RELU) v[j] = fmaxf(v[j], 0.0f);
        }
        *(uint2*)(Z + (size_t)node * F + l * 4) = uint2{pack2bf(v[0], v[1]), pack2bf(v[2], v[3])};
    }
}

// ===== decode via MFMA: 32 edges per wave (two 16-edge groups) =====
__global__ void decode_mfma(const int* __restrict__ pos, const int* __restrict__ neg,
                            const short* __restrict__ Z, float* __restrict__ out) {
    int wid = threadIdx.x >> 6;
    int lane = threadIdx.x & 63;
    int l15 = lane & 15;
    int quad = lane >> 4;
    int e0 = (blockIdx.x * 4 + wid) * 32;
    if (e0 >= N_POS + N_NEG) return;
    const int* bp = (e0 < N_POS) ? pos : (neg - N_POS);
    int eA = e0 + l15;
    int eB = e0 + 16 + l15;
    int aA = bp[eA], bA = bp[600000 + eA];
    int aB = bp[eB], bB = bp[600000 + eB];

    const short* zaA = Z + (size_t)aA * OUT_CH + quad * 8;
    const short* zbA = Z + (size_t)bA * OUT_CH + quad * 8;
    const short* zaB = Z + (size_t)aB * OUT_CH + quad * 8;
    const short* zbB = Z + (size_t)bB * OUT_CH + quad * 8;
    bf16x8 a0A = *(const bf16x8*)(zaA);
    bf16x8 a1A = *(const bf16x8*)(zaA + 32);
    bf16x8 b0A = *(const bf16x8*)(zbA);
    bf16x8 b1A = *(const bf16x8*)(zbA + 32);
    bf16x8 a0B = *(const bf16x8*)(zaB);
    bf16x8 a1B = *(const bf16x8*)(zaB + 32);
    bf16x8 b0B = *(const bf16x8*)(zbB);
    bf16x8 b1B = *(const bf16x8*)(zbB + 32);

    f32x4 accA = {}, accB = {};
    accA = __builtin_amdgcn_mfma_f32_16x16x32_bf16(a0A, b0A, accA, 0, 0, 0);
    accB = __builtin_amdgcn_mfma_f32_16x16x32_bf16(a0B, b0B, accB, 0, 0, 0);
    accA = __builtin_amdgcn_mfma_f32_16x16x32_bf16(a1A, b1A, accA, 0, 0, 0);
    accB = __builtin_amdgcn_mfma_f32_16x16x32_bf16(a1B, b1B, accB, 0, 0, 0);

    if (quad == (l15 >> 2)) {
        out[eA] = accA[l15 & 3];
        out[eB] = accB[l15 & 3];
    }
}

extern "C" void kernel_launch(void* const* d_in, const int* in_sizes, int n_in,
                              void* d_out, int out_size, void* d_ws, size_t ws_size,
                              hipStream_t stream) {
    const float* x = (const float*)d_in[0];
    const int* pos = (const int*)d_in[1];  // row0 = src, row1 = dst
    const int* neg = (const int*)d_in[2];
    const float* W1 = (const float*)d_in[3];
    const float* b1 = (const float*)d_in[4];
    const float* W2 = (const float*)d_in[5];
    const float* b2 = (const float*)d_in[6];
    float* out = (float*)d_out;

    // workspace layout (bf16 intermediates)
    ushort16* A = (ushort16*)d_ws;                      // h1 [N,128]; later h2 [N,64]
    ushort16* B = A + (size_t)N_NODES * 128;            // z1 [N,128]; later z2 [N,64]
    float* dinv = (float*)(B + (size_t)N_NODES * 128);  // [N]
    int* hist = (int*)(dinv + N_NODES);                 // [N]
    int* rowstart = hist + N_NODES;                     // [N+1]
    int* cursor = rowstart + N_NODES + 1;               // [N]
    int2* adjw = (int2*)(cursor + N_NODES);             // [N_POS] (adj, wgt) pairs
    int* partials = (int*)(adjw + N_POS);               // [128]
    ushort16* W1t = (ushort16*)(partials + 128);        // [128*128]
    ushort16* W2t = W1t + 128 * 128;                    // [64*128]

    const int* pos_src = pos;
    const int* pos_dst = pos + N_POS;

    constexpr int NB_SCAN = (N_NODES + 1023) / 1024;  // 98

    // ---- CSR build + dinv + weight convert ----
    hipMemsetAsync(hist, 0, N_NODES * sizeof(int), stream);
    hist_wt<<<NB_HIST + 96, 256, 0, stream>>>(pos_dst, hist, W1, W2, W1t, W2t);
    scan_reduce<<<NB_SCAN, 256, 0, stream>>>(hist, partials, N_NODES);
    scan_final<<<NB_SCAN, 256, 0, stream>>>(hist, partials, rowstart, cursor, dinv, N_NODES);

    // ---- csr_fill + layer-1 GEMM fused (independent work, one launch) ----
    csr_gemm1<<<NB_FILL + NB_GEMM1, 256, 0, stream>>>(pos_src, pos_dst, dinv, cursor, adjw, x,
                                                      W1t, A, N_NODES);

    // ---- layer 1 aggregation ----
    agg_pull<HIDDEN, true><<<(N_NODES + 15) / 16, 256, 0, stream>>>(rowstart, adjw, dinv, A, b1,
                                                                    B, N_NODES);

    // ---- layer 2 ----
    ushort16* h2 = A;  // [N,64]
    gemm_mfma<OUT_CH, true><<<(N_NODES + 63) / 64, 256, 0, stream>>>(B, W2t, h2, N_NODES);
    ushort16* z2 = B;  // [N,64]
    agg_pull<OUT_CH, false><<<(N_NODES + 15) / 16, 256, 0, stream>>>(rowstart, adjw, dinv, h2, b2,
                                                                     z2, N_NODES);

    // ---- decode (32 edges/wave, 128/block) ----
    decode_mfma<<<(N_POS + N_NEG) / 128, 256, 0, stream>>>(pos, neg, (const short*)z2, out);
}